// Round 1
// baseline (726.536 us; speedup 1.0000x reference)
//
#include <hip/hip_runtime.h>
#include <hip/hip_bf16.h>
#include <math.h>

#define B_ 2
#define NA_ 4096
#define NR_ 512
#define D_ 128
#define H_ 8
#define DH_ 16
#define NLOCAL_ 5
#define NIPA_ 4
#define NITER_ 3

__device__ __forceinline__ float gelu_tanh(float x) {
  float x3 = x * x * x;
  return 0.5f * x * (1.0f + tanhf(0.7978845608028654f * (x + 0.044715f * x3)));
}

// ---------------- atom features + pooled sums (atomic) ----------------
__global__ void k_atom_pool(const float* __restrict__ coords, const int* __restrict__ atype,
                            const int* __restrict__ rtype, const int* __restrict__ res_map,
                            const float* __restrict__ atom_emb, const float* __restrict__ res_emb,
                            const float* __restrict__ coord_W, const float* __restrict__ coord_b,
                            float* __restrict__ sums, float* __restrict__ cnts) {
  int a = blockIdx.x;      // 0 .. B*NA-1
  int d = threadIdx.x;     // 0 .. 127
  int b = a / NA_;
  int at = atype[a], rt = rtype[a];
  float c0 = coords[a * 3 + 0], c1 = coords[a * 3 + 1], c2 = coords[a * 3 + 2];
  float f = atom_emb[at * D_ + d] + res_emb[rt * D_ + d] + c0 * coord_W[0 * D_ + d] +
            c1 * coord_W[1 * D_ + d] + c2 * coord_W[2 * D_ + d] + coord_b[d];
  int r = b * NR_ + res_map[a];
  atomicAdd(&sums[r * D_ + d], f);
  if (d == 0) atomicAdd(&cnts[r], 1.0f);
}

// ---------------- fold pair_W/pair_b into per-layer 4xH bias weights ----------------
__global__ void k_weff(const float* __restrict__ pair_W, const float* __restrict__ pair_b,
                       const float* __restrict__ Wb, float* __restrict__ weff,
                       float* __restrict__ beff) {
  int t = threadIdx.x;
  if (t >= NIPA_ * 5 * H_) return;  // 160
  int l = t / (5 * H_);
  int rest = t % (5 * H_);
  int c = rest / H_;  // 0..3 = pair_W rows, 4 = pair_b
  int h = rest % H_;
  const float* row = (c < 4) ? (pair_W + c * D_) : pair_b;
  float acc = 0.f;
  for (int d = 0; d < D_; d++) acc += row[d] * Wb[l * D_ * H_ + d * H_ + h];
  if (c < 4)
    weff[l * 4 * H_ + c * H_ + h] = acc;
  else
    beff[l * H_ + h] = acc;
}

// ---------------- fused 5-layer local MLP (reads pooled sums, divides) ----------------
__global__ void k_local(const float* __restrict__ sums, const float* __restrict__ cnts,
                        const float* __restrict__ local_W, const float* __restrict__ local_b,
                        float* __restrict__ feats) {
  int row = blockIdx.x;  // b*NR+i
  int tid = threadIdx.x;
  __shared__ float xs[D_];
  float cnt = cnts[row];
  float x = sums[row * D_ + tid] / (cnt + 1e-8f);
  xs[tid] = x;
  __syncthreads();
  for (int l = 0; l < NLOCAL_; l++) {
    const float* W = local_W + (size_t)l * D_ * D_;
    float acc = local_b[l * D_ + tid];
#pragma unroll 8
    for (int kk = 0; kk < D_; kk++) acc += xs[kk] * W[kk * D_ + tid];
    float y = gelu_tanh(acc) + xs[tid];
    __syncthreads();
    xs[tid] = y;
    __syncthreads();
  }
  feats[row * D_ + tid] = xs[tid];
}

// ---------------- QKV projections for one IPA layer ----------------
__global__ void k_qkv(const float* __restrict__ feats, const float* __restrict__ Wq,
                      const float* __restrict__ Wk, const float* __restrict__ Wv,
                      float* __restrict__ q, float* __restrict__ k, float* __restrict__ v,
                      int l) {
  int row = blockIdx.x;
  int tid = threadIdx.x;
  __shared__ float xs[D_];
  xs[tid] = feats[row * D_ + tid];
  __syncthreads();
  const float* wq = Wq + (size_t)l * D_ * D_;
  const float* wk = Wk + (size_t)l * D_ * D_;
  const float* wv = Wv + (size_t)l * D_ * D_;
  float aq = 0.f, ak = 0.f, av = 0.f;
#pragma unroll 8
  for (int kk = 0; kk < D_; kk++) {
    float x = xs[kk];
    aq += x * wq[kk * D_ + tid];
    ak += x * wk[kk * D_ + tid];
    av += x * wv[kk * D_ + tid];
  }
  q[row * D_ + tid] = aq;
  k[row * D_ + tid] = ak;
  v[row * D_ + tid] = av;
}

// ---------------- fused attention for one (b,h), 32 queries per block ----------------
__launch_bounds__(256) __global__
void k_attn(const float* __restrict__ q, const float* __restrict__ k,
            const float* __restrict__ v, const float* __restrict__ curT,
            const float* __restrict__ res_mask, const float* __restrict__ weff,
            const float* __restrict__ beff, float* __restrict__ o, int l) {
  int qt = blockIdx.x;       // 0..15 (query tile of 32)
  int bh = blockIdx.y;       // 0..15
  int b = bh >> 3, h = bh & 7;

  __shared__ float ks[NR_][17];  // +1 pad: kills stride-16 bank conflicts
  __shared__ float vs[NR_][17];
  __shared__ float ts[NR_][3];
  __shared__ float ms[NR_];
  __shared__ float ps[4][NR_];

  int tid = threadIdx.x;
  for (int idx = tid; idx < NR_ * DH_; idx += 256) {
    int j = idx >> 4, d = idx & 15;
    ks[j][d] = k[(b * NR_ + j) * D_ + h * DH_ + d];
    vs[j][d] = v[(b * NR_ + j) * D_ + h * DH_ + d];
  }
  for (int idx = tid; idx < NR_; idx += 256) {
    ts[idx][0] = curT[(b * NR_ + idx) * 3 + 0];
    ts[idx][1] = curT[(b * NR_ + idx) * 3 + 1];
    ts[idx][2] = curT[(b * NR_ + idx) * 3 + 2];
    ms[idx] = res_mask[b * NR_ + idx];
  }
  __syncthreads();

  float c0 = weff[l * 32 + 0 * 8 + h];
  float c1 = weff[l * 32 + 1 * 8 + h];
  float c2 = weff[l * 32 + 2 * 8 + h];
  float c3 = weff[l * 32 + 3 * 8 + h];
  float be = beff[l * 8 + h];

  int w = tid >> 6, lane = tid & 63;

  for (int it = 0; it < 8; it++) {
    int i = qt * 32 + w * 8 + it;
    float qreg[16];
#pragma unroll
    for (int d = 0; d < 16; d++) qreg[d] = q[(b * NR_ + i) * D_ + h * DH_ + d];
    float tix = ts[i][0], tiy = ts[i][1], tiz = ts[i][2];

    float lg[8];
    float lmax = -1e30f;
#pragma unroll
    for (int jj = 0; jj < 8; jj++) {
      int j = lane + 64 * jj;
      float dot = 0.f;
#pragma unroll
      for (int d = 0; d < 16; d++) dot += qreg[d] * ks[j][d];
      float rx = tix - ts[j][0], ry = tiy - ts[j][1], rz = tiz - ts[j][2];
      float dist = sqrtf(rx * rx + ry * ry + rz * rz);
      float L = dot * 0.25f + c0 * rx + c1 * ry + c2 * rz + c3 * dist + be;
      if (ms[j] <= 0.f) L = -1e9f;
      lg[jj] = L;
      lmax = fmaxf(lmax, L);
    }
#pragma unroll
    for (int m = 1; m < 64; m <<= 1) lmax = fmaxf(lmax, __shfl_xor(lmax, m, 64));
    float lsum = 0.f;
#pragma unroll
    for (int jj = 0; jj < 8; jj++) {
      float p = __expf(lg[jj] - lmax);
      ps[w][lane + 64 * jj] = p;
      lsum += p;
    }
#pragma unroll
    for (int m = 1; m < 64; m <<= 1) lsum += __shfl_xor(lsum, m, 64);
    __syncthreads();  // ps visible (uniform loop, cheap)

    // PV: 4 chunks of 128 j's; lane = chunk*16 + d
    int d = lane & 15, chunk = lane >> 4;
    float acc = 0.f;
#pragma unroll 4
    for (int jj = 0; jj < 128; jj++) {
      int j = 4 * jj + chunk;  // consecutive banks across chunks
      acc += ps[w][j] * vs[j][d];
    }
    acc += __shfl_xor(acc, 16, 64);
    acc += __shfl_xor(acc, 32, 64);
    if (lane < 16) o[(b * NR_ + i) * D_ + h * DH_ + d] = acc / lsum;
    __syncthreads();
  }
}

// ---------------- output projection + residual (in-place on feats) ----------------
__global__ void k_oproj(const float* __restrict__ o, const float* __restrict__ Wo,
                        const float* __restrict__ bo, float* __restrict__ feats, int l) {
  int row = blockIdx.x;
  int tid = threadIdx.x;
  __shared__ float xs[D_];
  xs[tid] = o[row * D_ + tid];
  __syncthreads();
  const float* W = Wo + (size_t)l * D_ * D_;
  float acc = bo[l * D_ + tid];
#pragma unroll 8
  for (int kk = 0; kk < D_; kk++) acc += xs[kk] * W[kk * D_ + tid];
  feats[row * D_ + tid] += acc;
}

// ---------------- head projection + quaternion frame update ----------------
__global__ void k_head(const float* __restrict__ feats, const float* __restrict__ head_W,
                       const float* __restrict__ head_b, const float* __restrict__ res_mask,
                       float* __restrict__ curR, float* __restrict__ curT) {
  int r = blockIdx.x * blockDim.x + threadIdx.x;
  if (r >= B_ * NR_) return;
  float u[6];
#pragma unroll
  for (int c = 0; c < 6; c++) u[c] = head_b[c];
  for (int dd = 0; dd < D_; dd++) {
    float f = feats[r * D_ + dd];
#pragma unroll
    for (int c = 0; c < 6; c++) u[c] += f * head_W[dd * 6 + c];
  }
  float vx = u[0], vy = u[1], vz = u[2];
  float inv = rsqrtf(1.f + vx * vx + vy * vy + vz * vz);
  float w = inv, x = vx * inv, y = vy * inv, z = vz * inv;
  float Rd[9];
  Rd[0] = 1.f - 2.f * (y * y + z * z); Rd[1] = 2.f * (x * y - w * z); Rd[2] = 2.f * (x * z + w * y);
  Rd[3] = 2.f * (x * y + w * z); Rd[4] = 1.f - 2.f * (x * x + z * z); Rd[5] = 2.f * (y * z - w * x);
  Rd[6] = 2.f * (x * z - w * y); Rd[7] = 2.f * (y * z + w * x); Rd[8] = 1.f - 2.f * (x * x + y * y);
  float Ro[9];
#pragma unroll
  for (int c = 0; c < 9; c++) Ro[c] = curR[r * 9 + c];
  float Rn[9];
#pragma unroll
  for (int i = 0; i < 3; i++)
#pragma unroll
    for (int kk = 0; kk < 3; kk++)
      Rn[i * 3 + kk] = Rd[i * 3 + 0] * Ro[0 * 3 + kk] + Rd[i * 3 + 1] * Ro[1 * 3 + kk] +
                       Rd[i * 3 + 2] * Ro[2 * 3 + kk];
  float tx = curT[r * 3 + 0], ty = curT[r * 3 + 1], tz = curT[r * 3 + 2];
  float ux = u[3], uy = u[4], uz = u[5];
  float ntx = tx + Rn[0] * ux + Rn[1] * uy + Rn[2] * uz;
  float nty = ty + Rn[3] * ux + Rn[4] * uy + Rn[5] * uz;
  float ntz = tz + Rn[6] * ux + Rn[7] * uy + Rn[8] * uz;
  float m = res_mask[r];
#pragma unroll
  for (int c = 0; c < 9; c++) curR[r * 9 + c] = Rn[c];
  curT[r * 3 + 0] = ntx * m;
  curT[r * 3 + 1] = nty * m;
  curT[r * 3 + 2] = ntz * m;
}

// ---------------- final frame composition + output write ----------------
__global__ void k_final(const float* __restrict__ coords, const int* __restrict__ res_map,
                        const float* __restrict__ rots_bad, const float* __restrict__ trans_bad,
                        const float* __restrict__ curR, const float* __restrict__ curT,
                        float* __restrict__ out) {
  int a = blockIdx.x * blockDim.x + threadIdx.x;  // 0..B*NA-1
  if (a < B_ * NR_) {
#pragma unroll
    for (int c = 0; c < 9; c++) out[a * 9 + c] = curR[a * 9 + c];
    out[B_ * NR_ * 9 + a * 3 + 0] = curT[a * 3 + 0];
    out[B_ * NR_ * 9 + a * 3 + 1] = curT[a * 3 + 1];
    out[B_ * NR_ * 9 + a * 3 + 2] = curT[a * 3 + 2];
  }
  if (a >= B_ * NA_) return;
  int b = a / NA_;
  int r = b * NR_ + res_map[a];
  float x0 = coords[a * 3 + 0], x1 = coords[a * 3 + 1], x2 = coords[a * 3 + 2];
  float R0[9], Rc[9];
#pragma unroll
  for (int c = 0; c < 9; c++) { R0[c] = rots_bad[r * 9 + c]; Rc[c] = curR[r * 9 + c]; }
  float t0x = trans_bad[r * 3 + 0], t0y = trans_bad[r * 3 + 1], t0z = trans_bad[r * 3 + 2];
  float dx = x0 - t0x, dy = x1 - t0y, dz = x2 - t0z;
  // local = R0^T (x - t0)
  float lx = R0[0] * dx + R0[3] * dy + R0[6] * dz;
  float ly = R0[1] * dx + R0[4] * dy + R0[7] * dz;
  float lz = R0[2] * dx + R0[5] * dy + R0[8] * dz;
  // final = Rc^T local + tc
  float tcx = curT[r * 3 + 0], tcy = curT[r * 3 + 1], tcz = curT[r * 3 + 2];
  float fx = Rc[0] * lx + Rc[3] * ly + Rc[6] * lz + tcx;
  float fy = Rc[1] * lx + Rc[4] * ly + Rc[7] * lz + tcy;
  float fz = Rc[2] * lx + Rc[5] * ly + Rc[8] * lz + tcz;
  int off = B_ * NR_ * 12;
  out[off + a * 3 + 0] = fx;
  out[off + a * 3 + 1] = fy;
  out[off + a * 3 + 2] = fz;
}

extern "C" void kernel_launch(void* const* d_in, const int* in_sizes, int n_in,
                              void* d_out, int out_size, void* d_ws, size_t ws_size,
                              hipStream_t stream) {
  const float* coords    = (const float*)d_in[0];
  const int*   atype     = (const int*)d_in[1];
  const int*   rtype     = (const int*)d_in[2];
  // d_in[3] = mask (unused by reference)
  const float* res_mask  = (const float*)d_in[4];
  const int*   res_map   = (const int*)d_in[5];
  const float* rots_bad  = (const float*)d_in[6];
  const float* trans_bad = (const float*)d_in[7];
  const float* atom_emb  = (const float*)d_in[8];
  const float* res_emb   = (const float*)d_in[9];
  const float* coord_W   = (const float*)d_in[10];
  const float* coord_b   = (const float*)d_in[11];
  const float* local_W   = (const float*)d_in[12];
  const float* local_b   = (const float*)d_in[13];
  const float* pair_W    = (const float*)d_in[14];
  const float* pair_b    = (const float*)d_in[15];
  const float* Wq        = (const float*)d_in[16];
  const float* Wk        = (const float*)d_in[17];
  const float* Wv        = (const float*)d_in[18];
  const float* Wb        = (const float*)d_in[19];
  const float* Wo        = (const float*)d_in[20];
  const float* bo        = (const float*)d_in[21];
  const float* head_W    = (const float*)d_in[22];
  const float* head_b    = (const float*)d_in[23];

  float* ws = (float*)d_ws;
  float* sums = ws;                 // B*NR*D = 131072
  float* cnts = sums + 131072;      // 1024
  float* feats = cnts + 1024;       // 131072
  float* qb = feats + 131072;       // 131072
  float* kb = qb + 131072;          // 131072
  float* vb = kb + 131072;          // 131072
  float* ob = vb + 131072;          // 131072
  float* weff = ob + 131072;        // 128
  float* beff = weff + 128;         // 32
  float* curR = beff + 32;          // 9216
  float* curT = curR + 9216;        // 3072

  hipMemsetAsync(sums, 0, (131072 + 1024) * sizeof(float), stream);
  hipMemcpyAsync(curR, rots_bad, 9216 * sizeof(float), hipMemcpyDeviceToDevice, stream);
  hipMemcpyAsync(curT, trans_bad, 3072 * sizeof(float), hipMemcpyDeviceToDevice, stream);

  k_weff<<<1, 192, 0, stream>>>(pair_W, pair_b, Wb, weff, beff);
  k_atom_pool<<<B_ * NA_, D_, 0, stream>>>(coords, atype, rtype, res_map, atom_emb, res_emb,
                                           coord_W, coord_b, sums, cnts);

  for (int iter = 0; iter < NITER_; iter++) {
    k_local<<<B_ * NR_, D_, 0, stream>>>(sums, cnts, local_W, local_b, feats);
    for (int l = 0; l < NIPA_; l++) {
      k_qkv<<<B_ * NR_, D_, 0, stream>>>(feats, Wq, Wk, Wv, qb, kb, vb, l);
      k_attn<<<dim3(NR_ / 32, B_ * H_), 256, 0, stream>>>(qb, kb, vb, curT, res_mask, weff,
                                                          beff, ob, l);
      k_oproj<<<B_ * NR_, D_, 0, stream>>>(ob, Wo, bo, feats, l);
    }
    k_head<<<(B_ * NR_ + 255) / 256, 256, 0, stream>>>(feats, head_W, head_b, res_mask, curR,
                                                       curT);
  }
  k_final<<<(B_ * NA_ + 255) / 256, 256, 0, stream>>>(coords, res_map, rots_bad, trans_bad,
                                                      curR, curT, (float*)d_out);
}

// Round 2
// 456.577 us; speedup vs baseline: 1.5913x; 1.5913x over previous
//
#include <hip/hip_runtime.h>
#include <hip/hip_bf16.h>
#include <math.h>

#define B_ 2
#define NA_ 4096
#define NR_ 512
#define D_ 128
#define H_ 8
#define DH_ 16
#define NLOCAL_ 5
#define NIPA_ 4
#define NITER_ 3

__device__ __forceinline__ float gelu_tanh(float x) {
  float x3 = x * x * x;
  return 0.5f * x * (1.0f + tanhf(0.7978845608028654f * (x + 0.044715f * x3)));
}

// pack two floats as bf16 (RNE-ish) into one uint: lo in low half, hi in high half
__device__ __forceinline__ unsigned int pack_bf(float lo, float hi) {
  unsigned int a = __float_as_uint(lo);
  unsigned int b = __float_as_uint(hi);
  a = (a + 0x7fffu + ((a >> 16) & 1u)) >> 16;
  b = (b + 0x7fffu + ((b >> 16) & 1u)) & 0xffff0000u;
  return b | a;
}

// ---------------- atom features + pooled sums (atomic) ----------------
__global__ void k_atom_pool(const float* __restrict__ coords, const int* __restrict__ atype,
                            const int* __restrict__ rtype, const int* __restrict__ res_map,
                            const float* __restrict__ atom_emb, const float* __restrict__ res_emb,
                            const float* __restrict__ coord_W, const float* __restrict__ coord_b,
                            float* __restrict__ sums, float* __restrict__ cnts) {
  int a = blockIdx.x;      // 0 .. B*NA-1
  int d = threadIdx.x;     // 0 .. 127
  int b = a / NA_;
  int at = atype[a], rt = rtype[a];
  float c0 = coords[a * 3 + 0], c1 = coords[a * 3 + 1], c2 = coords[a * 3 + 2];
  float f = atom_emb[at * D_ + d] + res_emb[rt * D_ + d] + c0 * coord_W[0 * D_ + d] +
            c1 * coord_W[1 * D_ + d] + c2 * coord_W[2 * D_ + d] + coord_b[d];
  int r = b * NR_ + res_map[a];
  atomicAdd(&sums[r * D_ + d], f);
  if (d == 0) atomicAdd(&cnts[r], 1.0f);
}

// ---------------- fold pair_W/pair_b into per-layer 4xH bias weights ----------------
__global__ void k_weff(const float* __restrict__ pair_W, const float* __restrict__ pair_b,
                       const float* __restrict__ Wb, float* __restrict__ weff,
                       float* __restrict__ beff) {
  int t = threadIdx.x;
  if (t >= NIPA_ * 5 * H_) return;  // 160
  int l = t / (5 * H_);
  int rest = t % (5 * H_);
  int c = rest / H_;  // 0..3 = pair_W rows, 4 = pair_b
  int h = rest % H_;
  const float* row = (c < 4) ? (pair_W + c * D_) : pair_b;
  float acc = 0.f;
  for (int d = 0; d < D_; d++) acc += row[d] * Wb[l * D_ * H_ + d * H_ + h];
  if (c < 4)
    weff[l * 4 * H_ + c * H_ + h] = acc;
  else
    beff[l * H_ + h] = acc;
}

// ---------------- fused 5-layer local MLP + layer-0 QKV ----------------
__global__ void k_local_qkv(const float* __restrict__ sums, const float* __restrict__ cnts,
                            const float* __restrict__ local_W, const float* __restrict__ local_b,
                            const float* __restrict__ Wq, const float* __restrict__ Wk,
                            const float* __restrict__ Wv, float* __restrict__ feats,
                            float* __restrict__ q, float* __restrict__ k, float* __restrict__ v) {
  int row = blockIdx.x;  // b*NR+i
  int tid = threadIdx.x;
  __shared__ float xs[D_];
  float cnt = cnts[row];
  float x = sums[row * D_ + tid] / (cnt + 1e-8f);
  xs[tid] = x;
  __syncthreads();
  for (int l = 0; l < NLOCAL_; l++) {
    const float* W = local_W + (size_t)l * D_ * D_;
    float acc = local_b[l * D_ + tid];
#pragma unroll 8
    for (int kk = 0; kk < D_; kk++) acc += xs[kk] * W[kk * D_ + tid];
    float y = gelu_tanh(acc) + xs[tid];
    __syncthreads();
    xs[tid] = y;
    __syncthreads();
  }
  feats[row * D_ + tid] = xs[tid];
  // layer-0 QKV
  float aq = 0.f, ak = 0.f, av = 0.f;
#pragma unroll 8
  for (int kk = 0; kk < D_; kk++) {
    float xv = xs[kk];
    aq += xv * Wq[kk * D_ + tid];
    ak += xv * Wk[kk * D_ + tid];
    av += xv * Wv[kk * D_ + tid];
  }
  q[row * D_ + tid] = aq;
  k[row * D_ + tid] = ak;
  v[row * D_ + tid] = av;
}

// ---------------- fused attention for one (b,h), 16 queries per block ----------------
__launch_bounds__(256) __global__
void k_attn(const float* __restrict__ q, const float* __restrict__ k,
            const float* __restrict__ v, const float* __restrict__ curT,
            const float* __restrict__ res_mask, const float* __restrict__ weff,
            const float* __restrict__ beff, float* __restrict__ o, int l) {
  int qt = blockIdx.x;       // 0..31 (query tile of 16)
  int bh = blockIdx.y;       // 0..15
  int b = bh >> 3, h = bh & 7;

  __shared__ unsigned int ks[NR_][9];  // bf16x2 packed, pad 9 (stride 9 -> conflict-free)
  __shared__ unsigned int vs[NR_][9];
  __shared__ float ts[NR_][3];
  __shared__ float ms[NR_];
  __shared__ float ps[4][NR_];

  int tid = threadIdx.x;
  const float* kbase = k + (size_t)b * NR_ * D_ + h * DH_;
  const float* vbase = v + (size_t)b * NR_ * D_ + h * DH_;
  for (int idx = tid; idx < NR_ * 8; idx += 256) {
    int row = idx >> 3, u = idx & 7;
    float2 k2 = *(const float2*)(kbase + row * D_ + 2 * u);
    float2 v2 = *(const float2*)(vbase + row * D_ + 2 * u);
    ks[row][u] = pack_bf(k2.x, k2.y);
    vs[row][u] = pack_bf(v2.x, v2.y);
  }
  for (int idx = tid; idx < NR_; idx += 256) {
    ts[idx][0] = curT[(b * NR_ + idx) * 3 + 0];
    ts[idx][1] = curT[(b * NR_ + idx) * 3 + 1];
    ts[idx][2] = curT[(b * NR_ + idx) * 3 + 2];
    ms[idx] = res_mask[b * NR_ + idx];
  }
  __syncthreads();

  float c0 = weff[l * 32 + 0 * 8 + h];
  float c1 = weff[l * 32 + 1 * 8 + h];
  float c2 = weff[l * 32 + 2 * 8 + h];
  float c3 = weff[l * 32 + 3 * 8 + h];
  float be = beff[l * 8 + h];

  int w = tid >> 6, lane = tid & 63;

  for (int it = 0; it < 4; it++) {
    int i = qt * 16 + w * 4 + it;
    float qreg[16];
    const float* qrow = q + ((size_t)(b * NR_ + i)) * D_ + h * DH_;
#pragma unroll
    for (int d = 0; d < 16; d++) qreg[d] = qrow[d];
    float tix = ts[i][0], tiy = ts[i][1], tiz = ts[i][2];

    // logits + exp (no max subtraction: logits bounded ~|few|, exp cannot overflow;
    // softmax is shift-invariant so this matches the reference)
    float lsum = 0.f;
#pragma unroll
    for (int jj = 0; jj < 8; jj++) {
      int j = lane + 64 * jj;
      float dot = 0.f;
#pragma unroll
      for (int u = 0; u < 8; u++) {
        unsigned int pk = ks[j][u];
        float lo = __uint_as_float(pk << 16);
        float hi = __uint_as_float(pk & 0xffff0000u);
        dot += qreg[2 * u] * lo + qreg[2 * u + 1] * hi;
      }
      float rx = tix - ts[j][0], ry = tiy - ts[j][1], rz = tiz - ts[j][2];
      float dist = sqrtf(rx * rx + ry * ry + rz * rz);
      float L = dot * 0.25f + c0 * rx + c1 * ry + c2 * rz + c3 * dist + be;
      if (ms[j] <= 0.f) L = -1e9f;
      float p = __expf(L);
      ps[w][j] = p;   // wave-private: no block barrier needed (lockstep wave)
      lsum += p;
    }
#pragma unroll
    for (int m = 1; m < 64; m <<= 1) lsum += __shfl_xor(lsum, m, 64);

    // PV: lane = chunk*16 + d ; j = 4*jj + chunk
    int d = lane & 15, chunk = lane >> 4;
    int sh = (d & 1) ? 0 : 16;
    float acc = 0.f;
#pragma unroll 4
    for (int jj = 0; jj < 128; jj++) {
      int j = 4 * jj + chunk;
      unsigned int pk = vs[j][d >> 1];
      float vv = __uint_as_float((pk << sh) & 0xffff0000u);
      acc += ps[w][j] * vv;
    }
    acc += __shfl_xor(acc, 16, 64);
    acc += __shfl_xor(acc, 32, 64);
    if (lane < 16) o[(b * NR_ + i) * D_ + h * DH_ + d] = acc / lsum;
  }
}

// ---------------- oproj(l) + residual + QKV(l+1) ----------------
__global__ void k_oproj_qkv(const float* __restrict__ o, const float* __restrict__ Wo,
                            const float* __restrict__ bo, const float* __restrict__ Wq,
                            const float* __restrict__ Wk, const float* __restrict__ Wv,
                            float* __restrict__ feats, float* __restrict__ q,
                            float* __restrict__ k, float* __restrict__ v, int l, int ln) {
  int row = blockIdx.x;
  int tid = threadIdx.x;
  __shared__ float xs[D_];
  __shared__ float xs2[D_];
  xs[tid] = o[row * D_ + tid];
  __syncthreads();
  const float* W = Wo + (size_t)l * D_ * D_;
  float acc = bo[l * D_ + tid];
#pragma unroll 8
  for (int kk = 0; kk < D_; kk++) acc += xs[kk] * W[kk * D_ + tid];
  float f = feats[row * D_ + tid] + acc;
  feats[row * D_ + tid] = f;
  xs2[tid] = f;
  __syncthreads();
  const float* wq = Wq + (size_t)ln * D_ * D_;
  const float* wk = Wk + (size_t)ln * D_ * D_;
  const float* wv = Wv + (size_t)ln * D_ * D_;
  float aq = 0.f, ak = 0.f, av = 0.f;
#pragma unroll 8
  for (int kk = 0; kk < D_; kk++) {
    float xv = xs2[kk];
    aq += xv * wq[kk * D_ + tid];
    ak += xv * wk[kk * D_ + tid];
    av += xv * wv[kk * D_ + tid];
  }
  q[row * D_ + tid] = aq;
  k[row * D_ + tid] = ak;
  v[row * D_ + tid] = av;
}

// ---------------- oproj(3) + head projection + frame update ----------------
__global__ void k_oproj_head(const float* __restrict__ o, const float* __restrict__ Wo,
                             const float* __restrict__ bo, const float* __restrict__ feats,
                             const float* __restrict__ head_W, const float* __restrict__ head_b,
                             const float* __restrict__ res_mask, float* __restrict__ curR,
                             float* __restrict__ curT) {
  int row = blockIdx.x;
  int tid = threadIdx.x;
  __shared__ float xs[D_];
  __shared__ float wpart[2][6];
  xs[tid] = o[row * D_ + tid];
  __syncthreads();
  const int l = NIPA_ - 1;
  const float* W = Wo + (size_t)l * D_ * D_;
  float acc = bo[l * D_ + tid];
#pragma unroll 8
  for (int kk = 0; kk < D_; kk++) acc += xs[kk] * W[kk * D_ + tid];
  float f = feats[row * D_ + tid] + acc;
  float pc[6];
#pragma unroll
  for (int c = 0; c < 6; c++) pc[c] = f * head_W[tid * 6 + c];
#pragma unroll
  for (int m = 1; m < 64; m <<= 1)
#pragma unroll
    for (int c = 0; c < 6; c++) pc[c] += __shfl_xor(pc[c], m, 64);
  if ((tid & 63) == 0)
#pragma unroll
    for (int c = 0; c < 6; c++) wpart[tid >> 6][c] = pc[c];
  __syncthreads();
  if (tid == 0) {
    float u[6];
#pragma unroll
    for (int c = 0; c < 6; c++) u[c] = wpart[0][c] + wpart[1][c] + head_b[c];
    float vx = u[0], vy = u[1], vz = u[2];
    float inv = rsqrtf(1.f + vx * vx + vy * vy + vz * vz);
    float w = inv, x = vx * inv, y = vy * inv, z = vz * inv;
    float Rd[9];
    Rd[0] = 1.f - 2.f * (y * y + z * z); Rd[1] = 2.f * (x * y - w * z); Rd[2] = 2.f * (x * z + w * y);
    Rd[3] = 2.f * (x * y + w * z); Rd[4] = 1.f - 2.f * (x * x + z * z); Rd[5] = 2.f * (y * z - w * x);
    Rd[6] = 2.f * (x * z - w * y); Rd[7] = 2.f * (y * z + w * x); Rd[8] = 1.f - 2.f * (x * x + y * y);
    float Ro[9];
#pragma unroll
    for (int c = 0; c < 9; c++) Ro[c] = curR[row * 9 + c];
    float Rn[9];
#pragma unroll
    for (int i = 0; i < 3; i++)
#pragma unroll
      for (int kk = 0; kk < 3; kk++)
        Rn[i * 3 + kk] = Rd[i * 3 + 0] * Ro[0 * 3 + kk] + Rd[i * 3 + 1] * Ro[1 * 3 + kk] +
                         Rd[i * 3 + 2] * Ro[2 * 3 + kk];
    float tx = curT[row * 3 + 0], ty = curT[row * 3 + 1], tz = curT[row * 3 + 2];
    float ux = u[3], uy = u[4], uz = u[5];
    float ntx = tx + Rn[0] * ux + Rn[1] * uy + Rn[2] * uz;
    float nty = ty + Rn[3] * ux + Rn[4] * uy + Rn[5] * uz;
    float ntz = tz + Rn[6] * ux + Rn[7] * uy + Rn[8] * uz;
    float m = res_mask[row];
#pragma unroll
    for (int c = 0; c < 9; c++) curR[row * 9 + c] = Rn[c];
    curT[row * 3 + 0] = ntx * m;
    curT[row * 3 + 1] = nty * m;
    curT[row * 3 + 2] = ntz * m;
  }
}

// ---------------- final frame composition + output write ----------------
__global__ void k_final(const float* __restrict__ coords, const int* __restrict__ res_map,
                        const float* __restrict__ rots_bad, const float* __restrict__ trans_bad,
                        const float* __restrict__ curR, const float* __restrict__ curT,
                        float* __restrict__ out) {
  int a = blockIdx.x * blockDim.x + threadIdx.x;  // 0..B*NA-1
  if (a < B_ * NR_) {
#pragma unroll
    for (int c = 0; c < 9; c++) out[a * 9 + c] = curR[a * 9 + c];
    out[B_ * NR_ * 9 + a * 3 + 0] = curT[a * 3 + 0];
    out[B_ * NR_ * 9 + a * 3 + 1] = curT[a * 3 + 1];
    out[B_ * NR_ * 9 + a * 3 + 2] = curT[a * 3 + 2];
  }
  if (a >= B_ * NA_) return;
  int b = a / NA_;
  int r = b * NR_ + res_map[a];
  float x0 = coords[a * 3 + 0], x1 = coords[a * 3 + 1], x2 = coords[a * 3 + 2];
  float R0[9], Rc[9];
#pragma unroll
  for (int c = 0; c < 9; c++) { R0[c] = rots_bad[r * 9 + c]; Rc[c] = curR[r * 9 + c]; }
  float t0x = trans_bad[r * 3 + 0], t0y = trans_bad[r * 3 + 1], t0z = trans_bad[r * 3 + 2];
  float dx = x0 - t0x, dy = x1 - t0y, dz = x2 - t0z;
  // local = R0^T (x - t0)
  float lx = R0[0] * dx + R0[3] * dy + R0[6] * dz;
  float ly = R0[1] * dx + R0[4] * dy + R0[7] * dz;
  float lz = R0[2] * dx + R0[5] * dy + R0[8] * dz;
  // final = Rc^T local + tc
  float tcx = curT[r * 3 + 0], tcy = curT[r * 3 + 1], tcz = curT[r * 3 + 2];
  float fx = Rc[0] * lx + Rc[3] * ly + Rc[6] * lz + tcx;
  float fy = Rc[1] * lx + Rc[4] * ly + Rc[7] * lz + tcy;
  float fz = Rc[2] * lx + Rc[5] * ly + Rc[8] * lz + tcz;
  int off = B_ * NR_ * 12;
  out[off + a * 3 + 0] = fx;
  out[off + a * 3 + 1] = fy;
  out[off + a * 3 + 2] = fz;
}

extern "C" void kernel_launch(void* const* d_in, const int* in_sizes, int n_in,
                              void* d_out, int out_size, void* d_ws, size_t ws_size,
                              hipStream_t stream) {
  const float* coords    = (const float*)d_in[0];
  const int*   atype     = (const int*)d_in[1];
  const int*   rtype     = (const int*)d_in[2];
  // d_in[3] = mask (unused by reference)
  const float* res_mask  = (const float*)d_in[4];
  const int*   res_map   = (const int*)d_in[5];
  const float* rots_bad  = (const float*)d_in[6];
  const float* trans_bad = (const float*)d_in[7];
  const float* atom_emb  = (const float*)d_in[8];
  const float* res_emb   = (const float*)d_in[9];
  const float* coord_W   = (const float*)d_in[10];
  const float* coord_b   = (const float*)d_in[11];
  const float* local_W   = (const float*)d_in[12];
  const float* local_b   = (const float*)d_in[13];
  const float* pair_W    = (const float*)d_in[14];
  const float* pair_b    = (const float*)d_in[15];
  const float* Wq        = (const float*)d_in[16];
  const float* Wk        = (const float*)d_in[17];
  const float* Wv        = (const float*)d_in[18];
  const float* Wb        = (const float*)d_in[19];
  const float* Wo        = (const float*)d_in[20];
  const float* bo        = (const float*)d_in[21];
  const float* head_W    = (const float*)d_in[22];
  const float* head_b    = (const float*)d_in[23];

  float* ws = (float*)d_ws;
  float* sums = ws;                 // B*NR*D = 131072
  float* cnts = sums + 131072;      // 1024
  float* feats = cnts + 1024;       // 131072
  float* qb = feats + 131072;       // 131072
  float* kb = qb + 131072;          // 131072
  float* vb = kb + 131072;          // 131072
  float* ob = vb + 131072;          // 131072
  float* weff = ob + 131072;        // 128
  float* beff = weff + 128;         // 32
  float* curR = beff + 32;          // 9216
  float* curT = curR + 9216;        // 3072

  hipMemsetAsync(sums, 0, (131072 + 1024) * sizeof(float), stream);
  hipMemcpyAsync(curR, rots_bad, 9216 * sizeof(float), hipMemcpyDeviceToDevice, stream);
  hipMemcpyAsync(curT, trans_bad, 3072 * sizeof(float), hipMemcpyDeviceToDevice, stream);

  k_weff<<<1, 192, 0, stream>>>(pair_W, pair_b, Wb, weff, beff);
  k_atom_pool<<<B_ * NA_, D_, 0, stream>>>(coords, atype, rtype, res_map, atom_emb, res_emb,
                                           coord_W, coord_b, sums, cnts);

  for (int iter = 0; iter < NITER_; iter++) {
    k_local_qkv<<<B_ * NR_, D_, 0, stream>>>(sums, cnts, local_W, local_b, Wq, Wk, Wv, feats,
                                             qb, kb, vb);
    for (int l = 0; l < NIPA_; l++) {
      k_attn<<<dim3(NR_ / 16, B_ * H_), 256, 0, stream>>>(qb, kb, vb, curT, res_mask, weff,
                                                          beff, ob, l);
      if (l < NIPA_ - 1) {
        k_oproj_qkv<<<B_ * NR_, D_, 0, stream>>>(ob, Wo, bo, Wq, Wk, Wv, feats, qb, kb, vb,
                                                 l, l + 1);
      } else {
        k_oproj_head<<<B_ * NR_, D_, 0, stream>>>(ob, Wo, bo, feats, head_W, head_b, res_mask,
                                                  curR, curT);
      }
    }
  }
  k_final<<<(B_ * NA_ + 255) / 256, 256, 0, stream>>>(coords, res_map, rots_bad, trans_bad,
                                                      curR, curT, (float*)d_out);
}